// Round 3
// baseline (272.382 us; speedup 1.0000x reference)
//
#include <hip/hip_runtime.h>
#include <cstdint>

typedef unsigned short u16;
typedef __bf16 bf16x8 __attribute__((ext_vector_type(8)));
typedef short s16x4 __attribute__((ext_vector_type(4)));
typedef int s32x2 __attribute__((ext_vector_type(2)));
typedef float f32x4 __attribute__((ext_vector_type(4)));

// ---- bf16 helpers (RTNE, matching XLA/ml_dtypes) ----
__device__ __forceinline__ u16 f2bf(float f) {
    unsigned u = __float_as_uint(f);
    u = (u + 0x7fffu + ((u >> 16) & 1u)) >> 16;
    return (u16)u;
}
__device__ __forceinline__ float bf2f(u16 h) {
    return __uint_as_float(((unsigned)h) << 16);
}

// async global->LDS, 16B per lane; LDS dest = wave-uniform base + lane*16
__device__ __forceinline__ void glds16(const u16* g, u16* l) {
    __builtin_amdgcn_global_load_lds(
        (const __attribute__((address_space(1))) void*)g,
        (__attribute__((address_space(3))) void*)l, 16, 0, 0);
}

// pack 4 positive floats -> 4 bf16 (round-half-up via +0x8000; ties-only diff vs RTNE)
__device__ __forceinline__ s16x4 pack_bf4(float p0, float p1, float p2, float p3) {
    unsigned a0 = __float_as_uint(p0) + 0x8000u;
    unsigned a1 = __float_as_uint(p1) + 0x8000u;
    unsigned a2 = __float_as_uint(p2) + 0x8000u;
    unsigned a3 = __float_as_uint(p3) + 0x8000u;
    s32x2 pk = {(int)__builtin_amdgcn_perm(a1, a0, 0x07060302u),
                (int)__builtin_amdgcn_perm(a3, a2, 0x07060302u)};
    return __builtin_bit_cast(s16x4, pk);
}

#if __has_builtin(__builtin_amdgcn_mfma_f32_16x16x16bf16_1k)
#define MFMA16(a, b, c) __builtin_amdgcn_mfma_f32_16x16x16bf16_1k(a, b, c, 0, 0, 0)
#else
static __device__ __forceinline__ f32x4 mfma16_asm(s16x4 a, s16x4 b, f32x4 c) {
    asm("v_mfma_f32_16x16x16_bf16 %0, %1, %2, %0" : "+v"(c) : "v"(a), "v"(b));
    return c;
}
#define MFMA16(a, b, c) mfma16_asm(a, b, c)
#endif

// ============================================================================
// 1. prep: ternary-quantize both weights + cast x to bf16, one launch.
//    Quantization replicates the reference rounding order bit-exactly.
// ============================================================================
__global__ __launch_bounds__(256) void prep(
    const float* __restrict__ w_qkv, const float* __restrict__ w_proj,
    const float* __restrict__ x,
    u16* __restrict__ wqkv_b, u16* __restrict__ wproj_b, u16* __restrict__ xb) {
    int bid = blockIdx.x;
    if (bid < 10240) {
        const float* w; u16* o; int g;
        if (bid < 6144) { w = w_qkv; o = wqkv_b; g = bid * 4 + (threadIdx.x >> 6); }
        else { w = w_proj; o = wproj_b; g = (bid - 6144) * 4 + (threadIdx.x >> 6); }
        int lane = threadIdx.x & 63;
        float wf = w[(size_t)g * 64 + lane];
        u16 wb = f2bf(wf);
        float wbf = bf2f(wb);
        float a = fabsf(wbf);
        #pragma unroll
        for (int m = 1; m < 64; m <<= 1) a += __shfl_xor(a, m);
        float scale = bf2f(f2bf(a * (1.0f / 64.0f)));
        if (scale < 1e-8f) scale = 1e-8f;
        float t = bf2f(f2bf(wbf / scale));
        float q = rintf(t);
        q = fminf(1.0f, fmaxf(-1.0f, q));
        float wq = q * scale;
        float d = bf2f(f2bf(wq - wbf));
        o[(size_t)g * 64 + lane] = f2bf(wbf + d);
    } else {
        size_t i = ((size_t)(bid - 10240) * 256 + threadIdx.x) * 8;
        float4 a = *(const float4*)(x + i);
        float4 b = *(const float4*)(x + i + 4);
        u16 o[8] = {f2bf(a.x), f2bf(a.y), f2bf(a.z), f2bf(a.w),
                    f2bf(b.x), f2bf(b.y), f2bf(b.z), f2bf(b.w)};
        *(int4*)(xb + i) = *(const int4*)o;
    }
}

// ============================================================================
// 2. GEMM: C[M,N] fp32 = A[M,K]bf16 @ B[N,K]bf16^T.  128x128 tile, BK=32.
//    m97 structure: global_load_lds dwordx4 staging, unpadded LDS with
//    XOR((r>>1)&3) column-group swizzle -> 2-way banks (free).
// ============================================================================
__global__ __launch_bounds__(256) void gemm_bt(
    const u16* __restrict__ A, const u16* __restrict__ B,
    float* __restrict__ C, int M, int N, int K) {
    __shared__ u16 As[128 * 32];
    __shared__ u16 Bs[128 * 32];
    const int tid = threadIdx.x;
    const int lane = tid & 63, w = tid >> 6;
    const int quad = lane >> 4, l16 = lane & 15;
    const int m0 = blockIdx.y * 128, n0 = blockIdx.x * 128;
    const int wm = (w >> 1) * 64, wn = (w & 1) * 64;
    // staging geometry: instr i covers rows w*32+i*16+(lane>>2), group lane&3
    const int sr_ = w * 32 + (lane >> 2);
    const int sg_ = lane & 3;
    u16* Ald = As + w * 1024 + lane * 8;
    u16* Bld = Bs + w * 1024 + lane * 8;

    f32x4 acc[4][4];
    f32x4 zero = {0.f, 0.f, 0.f, 0.f};
    #pragma unroll
    for (int i = 0; i < 4; ++i)
        #pragma unroll
        for (int j = 0; j < 4; ++j) acc[i][j] = zero;

    // read-side swizzled offsets (element units)
    int aoff[4], boff[4];
    #pragma unroll
    for (int mi = 0; mi < 4; ++mi) {
        int r = wm + mi * 16 + l16;
        aoff[mi] = r * 32 + (quad ^ ((r >> 1) & 3)) * 8;
        int rb = wn + mi * 16 + l16;
        boff[mi] = rb * 32 + (quad ^ ((rb >> 1) & 3)) * 8;
    }

    for (int k0 = 0; k0 < K; k0 += 32) {
        __syncthreads();
        #pragma unroll
        for (int i = 0; i < 2; ++i) {
            int r = sr_ + i * 16;
            int g = sg_ ^ ((r >> 1) & 3);
            glds16(A + (size_t)(m0 + r) * K + k0 + g * 8, Ald + i * 512);
            glds16(B + (size_t)(n0 + r) * K + k0 + g * 8, Bld + i * 512);
        }
        __syncthreads();
        bf16x8 af[4], bfr[4];
        #pragma unroll
        for (int mi = 0; mi < 4; ++mi) af[mi]  = *(const bf16x8*)(As + aoff[mi]);
        #pragma unroll
        for (int ni = 0; ni < 4; ++ni) bfr[ni] = *(const bf16x8*)(Bs + boff[ni]);
        #pragma unroll
        for (int mi = 0; mi < 4; ++mi)
            #pragma unroll
            for (int ni = 0; ni < 4; ++ni)
                acc[mi][ni] = __builtin_amdgcn_mfma_f32_16x16x32_bf16(af[mi], bfr[ni], acc[mi][ni], 0, 0, 0);
    }
    #pragma unroll
    for (int mi = 0; mi < 4; ++mi)
        #pragma unroll
        for (int ni = 0; ni < 4; ++ni) {
            int rg = m0 + wm + mi * 16 + quad * 4;
            int cg = n0 + wn + ni * 16 + l16;
            float* cp = C + (size_t)rg * N + cg;
            #pragma unroll
            for (int r = 0; r < 4; ++r) cp[(size_t)r * N] = acc[mi][ni][r];
        }
}

// ============================================================================
// 3. Fusion: head-RMSNorm + RoPE + gain; Qb[b][h][s][d], Kb[b][kv][s][d],
//    V transposed Vt[b][kv][d][s].  (unchanged)
// ============================================================================
__global__ __launch_bounds__(256) void fuse_qkv(
    const float* __restrict__ qkv, const float* __restrict__ gain,
    u16* __restrict__ Qb, u16* __restrict__ Kb, u16* __restrict__ Vt) {
    __shared__ u16 Vs[16][264];
    const int tid = threadIdx.x;
    const int lane = tid & 63, wid = tid >> 6;
    const int lh = lane >> 4, l16 = lane & 15;
    const int T0 = blockIdx.x * 16;
    const int dbase = l16 * 4;
    const bool hi = dbase >= 32;
    const int ibase = hi ? dbase - 32 : dbase;
    const float sgn = hi ? -1.0f : 1.0f;
    const float eps = 1.1920929e-7f;

    float invf[4];
    #pragma unroll
    for (int j = 0; j < 4; ++j)
        invf[j] = (float)(1.0 / pow(10000.0, (double)(ibase + j) / 32.0));

    for (int i = 0; i < 4; ++i) {
        int tok = T0 + wid * 4 + i;
        int b = tok >> 11, s = tok & 2047;
        float cosv[4], sinv[4];
        #pragma unroll
        for (int j = 0; j < 4; ++j) {
            float fr = (float)s * invf[j];
            cosv[j] = cosf(fr);
            sinv[j] = sinf(fr);
        }
        const float* row = qkv + (size_t)tok * 1536;
        #pragma unroll
        for (int p = 0; p < 4; ++p) {
            int h = p * 4 + lh;
            float4 x = *(const float4*)(row + h * 64 + dbase);
            float ss = x.x * x.x + x.y * x.y + x.z * x.z + x.w * x.w;
            #pragma unroll
            for (int m = 1; m < 16; m <<= 1) ss += __shfl_xor(ss, m);
            float rn = 1.0f / sqrtf(ss * (1.0f / 64.0f) + eps);
            float xn0 = x.x * rn, xn1 = x.y * rn, xn2 = x.z * rn, xn3 = x.w * rn;
            float p0 = __shfl_xor(xn0, 8), p1 = __shfl_xor(xn1, 8);
            float p2 = __shfl_xor(xn2, 8), p3 = __shfl_xor(xn3, 8);
            float g = gain[h];
            u16 o[4] = {f2bf((xn0 * cosv[0] + sgn * p0 * sinv[0]) * g),
                        f2bf((xn1 * cosv[1] + sgn * p1 * sinv[1]) * g),
                        f2bf((xn2 * cosv[2] + sgn * p2 * sinv[2]) * g),
                        f2bf((xn3 * cosv[3] + sgn * p3 * sinv[3]) * g)};
            *(uint2*)(Qb + (((size_t)(b * 16 + h) * 2048 + s) * 64 + dbase)) = *(const uint2*)o;
        }
        {
            float4 x = *(const float4*)(row + 1024 + lh * 64 + dbase);
            float ss = x.x * x.x + x.y * x.y + x.z * x.z + x.w * x.w;
            #pragma unroll
            for (int m = 1; m < 16; m <<= 1) ss += __shfl_xor(ss, m);
            float rn = 1.0f / sqrtf(ss * (1.0f / 64.0f) + eps);
            float xn0 = x.x * rn, xn1 = x.y * rn, xn2 = x.z * rn, xn3 = x.w * rn;
            float p0 = __shfl_xor(xn0, 8), p1 = __shfl_xor(xn1, 8);
            float p2 = __shfl_xor(xn2, 8), p3 = __shfl_xor(xn3, 8);
            u16 o[4] = {f2bf(xn0 * cosv[0] + sgn * p0 * sinv[0]),
                        f2bf(xn1 * cosv[1] + sgn * p1 * sinv[1]),
                        f2bf(xn2 * cosv[2] + sgn * p2 * sinv[2]),
                        f2bf(xn3 * cosv[3] + sgn * p3 * sinv[3])};
            *(uint2*)(Kb + (((size_t)(b * 4 + lh) * 2048 + s) * 64 + dbase)) = *(const uint2*)o;
        }
        {
            float4 x = *(const float4*)(row + 1280 + lh * 64 + dbase);
            u16 o[4] = {f2bf(x.x), f2bf(x.y), f2bf(x.z), f2bf(x.w)};
            int sl = wid * 4 + i;
            *(uint2*)(&Vs[sl][lh * 64 + dbase]) = *(const uint2*)o;
        }
    }
    __syncthreads();
    {
        int kvh = tid >> 6, d = tid & 63;
        int b0 = T0 >> 11, s0 = T0 & 2047;
        u16 tmp[16];
        #pragma unroll
        for (int sl = 0; sl < 16; ++sl) tmp[sl] = Vs[sl][kvh * 64 + d];
        u16* dst = Vt + ((size_t)(b0 * 4 + kvh) * 64 + d) * 2048 + s0;
        *(int4*)(dst) = *(const int4*)(tmp);
        *(int4*)(dst + 8) = *(const int4*)(tmp + 8);
    }
}

// ============================================================================
// 4. Flash attention, transposed, Q-tile 128 (2 bands/wave), K-tile 64.
//    Single barrier/iter: glds double-buffer staging (XOR(r&7) swizzle,
//    conflict-free), K/V frags shared across bands, perm-packed P.
//    Grid: x = h+16*b (32), y: bq = 15-y (LPT).
// ============================================================================
__global__ __launch_bounds__(256) void attn(
    const u16* __restrict__ Qb, const u16* __restrict__ Kb,
    const u16* __restrict__ Vt, float* __restrict__ y) {
    __shared__ u16 Ks[2][64 * 64];
    __shared__ u16 Vsh[2][64 * 64];
    const int hb = blockIdx.x;
    const int h = hb & 15, b = hb >> 4;
    const int bq = 15 - blockIdx.y;
    const int q0 = bq * 128;
    const int kvh = h >> 2;
    const int tid = threadIdx.x, lane = tid & 63, w = tid >> 6;
    const int quad = lane >> 4, l16 = lane & 15;

    const u16* Qg = Qb + ((size_t)(b * 16 + h) * 2048 + q0) * 64;
    const u16* Kg = Kb + (size_t)(b * 4 + kvh) * 2048 * 64;
    const u16* Vg = Vt + (size_t)(b * 4 + kvh) * 64 * 2048;

    // Q fragments straight from global (once): band bi2, half hf
    bf16x8 qa[2][2];
    #pragma unroll
    for (int bi2 = 0; bi2 < 2; ++bi2)
        #pragma unroll
        for (int hf = 0; hf < 2; ++hf)
            qa[bi2][hf] = *(const bf16x8*)(Qg + (size_t)(bi2 * 64 + w * 16 + l16) * 64 + hf * 32 + quad * 8);

    // staging geometry: instr i covers rows w*16+i*8+(lane>>3), 16B-group lane&7
    const int sr_ = w * 16 + (lane >> 3);
    const int sg_ = lane & 7;
    const int sld = w * 1024 + lane * 8;   // element offset in a 64x64 tile

    const int nj = 2 * bq + 2;
    // stage tile 0
    #pragma unroll
    for (int i = 0; i < 2; ++i) {
        int r = sr_ + i * 8;
        int g = sg_ ^ (r & 7);
        glds16(Kg + (size_t)r * 64 + g * 8, &Ks[0][0] + sld + i * 512);
        glds16(Vg + (size_t)r * 2048 + g * 8, &Vsh[0][0] + sld + i * 512);
    }
    __syncthreads();

    f32x4 o0[4], o1[4];
    f32x4 zero = {0.f, 0.f, 0.f, 0.f};
    #pragma unroll
    for (int t = 0; t < 4; ++t) { o0[t] = zero; o1[t] = zero; }
    float m0 = -INFINITY, l0 = 0.f, m1 = -INFINITY, l1 = 0.f;
    const float sc = 0.18033688011112042f;  // 0.125 * log2(e)

    for (int j = 0; j < nj; ++j) {
        if (j + 1 < nj) {
            int jj = 64 * (j + 1), bi = (j + 1) & 1;
            #pragma unroll
            for (int i = 0; i < 2; ++i) {
                int r = sr_ + i * 8;
                int g = sg_ ^ (r & 7);
                glds16(Kg + (size_t)(jj + r) * 64 + g * 8, &Ks[bi][0] + sld + i * 512);
                glds16(Vg + (size_t)r * 2048 + jj + g * 8, &Vsh[bi][0] + sld + i * 512);
            }
        }
        const u16* Kt = &Ks[j & 1][0];
        const u16* Vtl = &Vsh[j & 1][0];
        const int d0 = 8 * bq + w - 4 * j;   // band0 diag t; band1 diag = d0+4
        const int d1 = d0 + 4;

        // S^T tiles; K frags shared by both bands
        f32x4 st0[4], st1[4];
        #pragma unroll
        for (int t = 0; t < 4; ++t) {
            if (t <= d1) {
                int rk = t * 16 + l16;
                bf16x8 kb0 = *(const bf16x8*)(Kt + rk * 64 + (quad ^ (rk & 7)) * 8);
                bf16x8 kb1 = *(const bf16x8*)(Kt + rk * 64 + ((quad + 4) ^ (rk & 7)) * 8);
                f32x4 s1 = __builtin_amdgcn_mfma_f32_16x16x32_bf16(kb0, qa[1][0], zero, 0, 0, 0);
                s1 = __builtin_amdgcn_mfma_f32_16x16x32_bf16(kb1, qa[1][1], s1, 0, 0, 0);
                st1[t] = s1;
                if (t <= d0) {
                    f32x4 s0 = __builtin_amdgcn_mfma_f32_16x16x32_bf16(kb0, qa[0][0], zero, 0, 0, 0);
                    s0 = __builtin_amdgcn_mfma_f32_16x16x32_bf16(kb1, qa[0][1], s0, 0, 0, 0);
                    st0[t] = s0;
                }
            }
        }

        s16x4 pf0[4], pf1[4];
        float alpha0 = 1.f, alpha1;
        // ---- band1 (always active) ----
        {
            float mx = -1e30f;
            #pragma unroll
            for (int t = 0; t < 4; ++t) {
                if (t <= d1) {
                    #pragma unroll
                    for (int r = 0; r < 4; ++r) {
                        float v = st1[t][r] * sc;
                        if (t == d1 && (quad * 4 + r > l16)) v = -1e30f;
                        st1[t][r] = v;
                        mx = fmaxf(mx, v);
                    }
                }
            }
            mx = fmaxf(mx, __shfl_xor(mx, 16));
            mx = fmaxf(mx, __shfl_xor(mx, 32));
            float mnew = fmaxf(m1, mx);
            alpha1 = __builtin_amdgcn_exp2f(m1 - mnew);
            m1 = mnew;
            float rs = 0.f;
            #pragma unroll
            for (int t = 0; t < 4; ++t) {
                if (t <= d1) {
                    float p0 = __builtin_amdgcn_exp2f(st1[t][0] - mnew);
                    float p1 = __builtin_amdgcn_exp2f(st1[t][1] - mnew);
                    float p2 = __builtin_amdgcn_exp2f(st1[t][2] - mnew);
                    float p3 = __builtin_amdgcn_exp2f(st1[t][3] - mnew);
                    rs += (p0 + p1) + (p2 + p3);
                    pf1[t] = pack_bf4(p0, p1, p2, p3);
                }
            }
            rs += __shfl_xor(rs, 16);
            rs += __shfl_xor(rs, 32);
            l1 = l1 * alpha1 + rs;
            #pragma unroll
            for (int t = 0; t < 4; ++t) o1[t] *= alpha1;
        }
        // ---- band0 (skip when fully masked) ----
        if (d0 >= 0) {
            float mx = -1e30f;
            #pragma unroll
            for (int t = 0; t < 4; ++t) {
                if (t <= d0) {
                    #pragma unroll
                    for (int r = 0; r < 4; ++r) {
                        float v = st0[t][r] * sc;
                        if (t == d0 && (quad * 4 + r > l16)) v = -1e30f;
                        st0[t][r] = v;
                        mx = fmaxf(mx, v);
                    }
                }
            }
            mx = fmaxf(mx, __shfl_xor(mx, 16));
            mx = fmaxf(mx, __shfl_xor(mx, 32));
            float mnew = fmaxf(m0, mx);
            alpha0 = __builtin_amdgcn_exp2f(m0 - mnew);
            m0 = mnew;
            float rs = 0.f;
            #pragma unroll
            for (int t = 0; t < 4; ++t) {
                if (t <= d0) {
                    float p0 = __builtin_amdgcn_exp2f(st0[t][0] - mnew);
                    float p1 = __builtin_amdgcn_exp2f(st0[t][1] - mnew);
                    float p2 = __builtin_amdgcn_exp2f(st0[t][2] - mnew);
                    float p3 = __builtin_amdgcn_exp2f(st0[t][3] - mnew);
                    rs += (p0 + p1) + (p2 + p3);
                    pf0[t] = pack_bf4(p0, p1, p2, p3);
                }
            }
            rs += __shfl_xor(rs, 16);
            rs += __shfl_xor(rs, 32);
            l0 = l0 * alpha0 + rs;
            #pragma unroll
            for (int t = 0; t < 4; ++t) o0[t] *= alpha0;
        }

        // PV: V frags shared by both bands
        #pragma unroll
        for (int dt = 0; dt < 4; ++dt) {
            int rv = dt * 16 + l16;
            #pragma unroll
            for (int kt = 0; kt < 4; ++kt) {
                if (kt <= d1) {
                    int gv = 2 * kt + (quad >> 1);
                    s16x4 va = *(const s16x4*)(Vtl + rv * 64 + (gv ^ (rv & 7)) * 8 + (quad & 1) * 4);
                    if (kt <= d0) o0[dt] = MFMA16(va, pf0[kt], o0[dt]);
                    o1[dt] = MFMA16(va, pf1[kt], o1[dt]);
                }
            }
        }
        __syncthreads();
    }
    // epilogue
    const float inv0 = 1.0f / l0, inv1 = 1.0f / l1;
    const size_t r0 = (size_t)b * 2048 + q0 + w * 16 + l16;
    #pragma unroll
    for (int dt = 0; dt < 4; ++dt) {
        f32x4 a = o0[dt] * inv0;
        f32x4 c = o1[dt] * inv1;
        *(f32x4*)(&y[r0 * 1024 + h * 64 + dt * 16 + quad * 4]) = a;
        *(f32x4*)(&y[(r0 + 64) * 1024 + h * 64 + dt * 16 + quad * 4]) = c;
    }
}

// ============================================================================
// 5. Row RMSNorm (dim 1024) -> bf16
// ============================================================================
__global__ __launch_bounds__(256) void rmsnorm_rows(
    const float* __restrict__ y, u16* __restrict__ yb) {
    __shared__ float red[4];
    const int row = blockIdx.x, tid = threadIdx.x;
    const float* p = y + (size_t)row * 1024 + tid * 4;
    float4 v = *(const float4*)p;
    float ss = v.x * v.x + v.y * v.y + v.z * v.z + v.w * v.w;
    #pragma unroll
    for (int m = 1; m < 64; m <<= 1) ss += __shfl_xor(ss, m);
    if ((tid & 63) == 0) red[tid >> 6] = ss;
    __syncthreads();
    float tot = red[0] + red[1] + red[2] + red[3];
    float rn = 1.0f / sqrtf(tot * (1.0f / 1024.0f) + 1.1920929e-7f);
    u16 o[4] = {f2bf(v.x * rn), f2bf(v.y * rn), f2bf(v.z * rn), f2bf(v.w * rn)};
    *(uint2*)(yb + (size_t)row * 1024 + tid * 4) = *(const uint2*)o;
}

// ============================================================================
// launch
// ============================================================================
extern "C" void kernel_launch(void* const* d_in, const int* in_sizes, int n_in,
                              void* d_out, int out_size, void* d_ws, size_t ws_size,
                              hipStream_t stream) {
    const float* x      = (const float*)d_in[0];
    const float* w_qkv  = (const float*)d_in[1];
    const float* w_proj = (const float*)d_in[2];
    const float* q_gain = (const float*)d_in[3];
    float* out = (float*)d_out;
    char* ws = (char*)d_ws;

    u16*   wqkv_b  = (u16*)(ws);                    // 3,145,728
    u16*   wproj_b = (u16*)(ws + 3145728);          // 2,097,152
    u16*   xb      = (u16*)(ws + 5242880);          // 8,388,608 (aliased: yb)
    float* qkv     = (float*)(ws + 13631488);       // 25,165,824 (aliased: y)
    u16*   Qb      = (u16*)(ws + 38797312);         // 8,388,608
    u16*   Kb      = (u16*)(ws + 47185920);         // 2,097,152
    u16*   Vt      = (u16*)(ws + 49283072);         // 2,097,152
    float* y  = qkv;
    u16*   yb = xb;

    prep<<<12288, 256, 0, stream>>>(w_qkv, w_proj, x, wqkv_b, wproj_b, xb);
    gemm_bt<<<dim3(12, 32), 256, 0, stream>>>(xb, wqkv_b, qkv, 4096, 1536, 1024);
    fuse_qkv<<<256, 256, 0, stream>>>(qkv, q_gain, Qb, Kb, Vt);
    attn<<<dim3(32, 16), 256, 0, stream>>>(Qb, Kb, Vt, y);
    rmsnorm_rows<<<4096, 256, 0, stream>>>(y, yb);
    gemm_bt<<<dim3(8, 32), 256, 0, stream>>>(yb, wproj_b, out, 4096, 1024, 1024);
}

// Round 4
// 237.070 us; speedup vs baseline: 1.1490x; 1.1490x over previous
//
#include <hip/hip_runtime.h>
#include <cstdint>

typedef unsigned short u16;
typedef __bf16 bf16x8 __attribute__((ext_vector_type(8)));
typedef short s16x4 __attribute__((ext_vector_type(4)));
typedef int s32x2 __attribute__((ext_vector_type(2)));
typedef float f32x4 __attribute__((ext_vector_type(4)));

// ---- bf16 helpers (RTNE, matching XLA/ml_dtypes) ----
__device__ __forceinline__ u16 f2bf(float f) {
    unsigned u = __float_as_uint(f);
    u = (u + 0x7fffu + ((u >> 16) & 1u)) >> 16;
    return (u16)u;
}
__device__ __forceinline__ float bf2f(u16 h) {
    return __uint_as_float(((unsigned)h) << 16);
}

// async global->LDS, 16B per lane; LDS dest = wave-uniform base + lane*16
__device__ __forceinline__ void glds16(const u16* g, u16* l) {
    __builtin_amdgcn_global_load_lds(
        (const __attribute__((address_space(1))) void*)g,
        (__attribute__((address_space(3))) void*)l, 16, 0, 0);
}

// pack 4 positive floats -> 4 bf16 (round-half-up; ties-only diff vs RTNE)
__device__ __forceinline__ s16x4 pack_bf4(float p0, float p1, float p2, float p3) {
    unsigned a0 = __float_as_uint(p0) + 0x8000u;
    unsigned a1 = __float_as_uint(p1) + 0x8000u;
    unsigned a2 = __float_as_uint(p2) + 0x8000u;
    unsigned a3 = __float_as_uint(p3) + 0x8000u;
    s32x2 pk = {(int)__builtin_amdgcn_perm(a1, a0, 0x07060302u),
                (int)__builtin_amdgcn_perm(a3, a2, 0x07060302u)};
    return __builtin_bit_cast(s16x4, pk);
}

#if __has_builtin(__builtin_amdgcn_mfma_f32_16x16x16bf16_1k)
#define MFMA16(a, b, c) __builtin_amdgcn_mfma_f32_16x16x16bf16_1k(a, b, c, 0, 0, 0)
#else
static __device__ __forceinline__ f32x4 mfma16_asm(s16x4 a, s16x4 b, f32x4 c) {
    asm("v_mfma_f32_16x16x16_bf16 %0, %1, %2, %0" : "+v"(c) : "v"(a), "v"(b));
    return c;
}
#define MFMA16(a, b, c) mfma16_asm(a, b, c)
#endif

// ============================================================================
// 1. prep: ternary-quantize both weights + cast x to bf16, one launch.
// ============================================================================
__global__ __launch_bounds__(256) void prep(
    const float* __restrict__ w_qkv, const float* __restrict__ w_proj,
    const float* __restrict__ x,
    u16* __restrict__ wqkv_b, u16* __restrict__ wproj_b, u16* __restrict__ xb) {
    int bid = blockIdx.x;
    if (bid < 10240) {
        const float* w; u16* o; int g;
        if (bid < 6144) { w = w_qkv; o = wqkv_b; g = bid * 4 + (threadIdx.x >> 6); }
        else { w = w_proj; o = wproj_b; g = (bid - 6144) * 4 + (threadIdx.x >> 6); }
        int lane = threadIdx.x & 63;
        float wf = w[(size_t)g * 64 + lane];
        u16 wb = f2bf(wf);
        float wbf = bf2f(wb);
        float a = fabsf(wbf);
        #pragma unroll
        for (int m = 1; m < 64; m <<= 1) a += __shfl_xor(a, m);
        float scale = bf2f(f2bf(a * (1.0f / 64.0f)));
        if (scale < 1e-8f) scale = 1e-8f;
        float t = bf2f(f2bf(wbf / scale));
        float q = rintf(t);
        q = fminf(1.0f, fmaxf(-1.0f, q));
        float wq = q * scale;
        float d = bf2f(f2bf(wq - wbf));
        o[(size_t)g * 64 + lane] = f2bf(wbf + d);
    } else {
        size_t i = ((size_t)(bid - 10240) * 256 + threadIdx.x) * 8;
        float4 a = *(const float4*)(x + i);
        float4 b = *(const float4*)(x + i + 4);
        u16 o[8] = {f2bf(a.x), f2bf(a.y), f2bf(a.z), f2bf(a.w),
                    f2bf(b.x), f2bf(b.y), f2bf(b.z), f2bf(b.w)};
        *(int4*)(xb + i) = *(const int4*)o;
    }
}

// ============================================================================
// 2. GEMM: C[M,N] fp32 = A[M,K]bf16 @ B[N,K]bf16^T.  128x128 tile, BK=32,
//    glds staging with XOR((r>>1)&3) swizzle.
// ============================================================================
__global__ __launch_bounds__(256) void gemm_bt(
    const u16* __restrict__ A, const u16* __restrict__ B,
    float* __restrict__ C, int M, int N, int K) {
    __shared__ u16 As[128 * 32];
    __shared__ u16 Bs[128 * 32];
    const int tid = threadIdx.x;
    const int lane = tid & 63, w = tid >> 6;
    const int quad = lane >> 4, l16 = lane & 15;
    const int m0 = blockIdx.y * 128, n0 = blockIdx.x * 128;
    const int wm = (w >> 1) * 64, wn = (w & 1) * 64;
    const int sr_ = w * 32 + (lane >> 2);
    const int sg_ = lane & 3;
    u16* Ald = As + w * 1024 + lane * 8;
    u16* Bld = Bs + w * 1024 + lane * 8;

    f32x4 acc[4][4];
    f32x4 zero = {0.f, 0.f, 0.f, 0.f};
    #pragma unroll
    for (int i = 0; i < 4; ++i)
        #pragma unroll
        for (int j = 0; j < 4; ++j) acc[i][j] = zero;

    int aoff[4], boff[4];
    #pragma unroll
    for (int mi = 0; mi < 4; ++mi) {
        int r = wm + mi * 16 + l16;
        aoff[mi] = r * 32 + (quad ^ ((r >> 1) & 3)) * 8;
        int rb = wn + mi * 16 + l16;
        boff[mi] = rb * 32 + (quad ^ ((rb >> 1) & 3)) * 8;
    }

    for (int k0 = 0; k0 < K; k0 += 32) {
        __syncthreads();
        #pragma unroll
        for (int i = 0; i < 2; ++i) {
            int r = sr_ + i * 16;
            int g = sg_ ^ ((r >> 1) & 3);
            glds16(A + (size_t)(m0 + r) * K + k0 + g * 8, Ald + i * 512);
            glds16(B + (size_t)(n0 + r) * K + k0 + g * 8, Bld + i * 512);
        }
        __syncthreads();
        bf16x8 af[4], bfr[4];
        #pragma unroll
        for (int mi = 0; mi < 4; ++mi) af[mi]  = *(const bf16x8*)(As + aoff[mi]);
        #pragma unroll
        for (int ni = 0; ni < 4; ++ni) bfr[ni] = *(const bf16x8*)(Bs + boff[ni]);
        #pragma unroll
        for (int mi = 0; mi < 4; ++mi)
            #pragma unroll
            for (int ni = 0; ni < 4; ++ni)
                acc[mi][ni] = __builtin_amdgcn_mfma_f32_16x16x32_bf16(af[mi], bfr[ni], acc[mi][ni], 0, 0, 0);
    }
    #pragma unroll
    for (int mi = 0; mi < 4; ++mi)
        #pragma unroll
        for (int ni = 0; ni < 4; ++ni) {
            int rg = m0 + wm + mi * 16 + quad * 4;
            int cg = n0 + wn + ni * 16 + l16;
            float* cp = C + (size_t)rg * N + cg;
            #pragma unroll
            for (int r = 0; r < 4; ++r) cp[(size_t)r * N] = acc[mi][ni][r];
        }
}

// ============================================================================
// 3. Fusion: head-RMSNorm + RoPE + gain; 8 tokens/block (512 blocks).
// ============================================================================
__global__ __launch_bounds__(256) void fuse_qkv(
    const float* __restrict__ qkv, const float* __restrict__ gain,
    u16* __restrict__ Qb, u16* __restrict__ Kb, u16* __restrict__ Vt) {
    __shared__ u16 Vs[8][264];
    const int tid = threadIdx.x;
    const int lane = tid & 63, wid = tid >> 6;
    const int lh = lane >> 4, l16 = lane & 15;
    const int T0 = blockIdx.x * 8;
    const int dbase = l16 * 4;
    const bool hi = dbase >= 32;
    const int ibase = hi ? dbase - 32 : dbase;
    const float sgn = hi ? -1.0f : 1.0f;
    const float eps = 1.1920929e-7f;

    float invf[4];
    #pragma unroll
    for (int j = 0; j < 4; ++j)
        invf[j] = (float)(1.0 / pow(10000.0, (double)(ibase + j) / 32.0));

    #pragma unroll
    for (int i = 0; i < 2; ++i) {
        int tok = T0 + wid * 2 + i;
        int b = tok >> 11, s = tok & 2047;
        float cosv[4], sinv[4];
        #pragma unroll
        for (int j = 0; j < 4; ++j) {
            float fr = (float)s * invf[j];
            cosv[j] = cosf(fr);
            sinv[j] = sinf(fr);
        }
        const float* row = qkv + (size_t)tok * 1536;
        #pragma unroll
        for (int p = 0; p < 4; ++p) {
            int h = p * 4 + lh;
            float4 x = *(const float4*)(row + h * 64 + dbase);
            float ss = x.x * x.x + x.y * x.y + x.z * x.z + x.w * x.w;
            #pragma unroll
            for (int m = 1; m < 16; m <<= 1) ss += __shfl_xor(ss, m);
            float rn = 1.0f / sqrtf(ss * (1.0f / 64.0f) + eps);
            float xn0 = x.x * rn, xn1 = x.y * rn, xn2 = x.z * rn, xn3 = x.w * rn;
            float p0 = __shfl_xor(xn0, 8), p1 = __shfl_xor(xn1, 8);
            float p2 = __shfl_xor(xn2, 8), p3 = __shfl_xor(xn3, 8);
            float g = gain[h];
            u16 o[4] = {f2bf((xn0 * cosv[0] + sgn * p0 * sinv[0]) * g),
                        f2bf((xn1 * cosv[1] + sgn * p1 * sinv[1]) * g),
                        f2bf((xn2 * cosv[2] + sgn * p2 * sinv[2]) * g),
                        f2bf((xn3 * cosv[3] + sgn * p3 * sinv[3]) * g)};
            *(uint2*)(Qb + (((size_t)(b * 16 + h) * 2048 + s) * 64 + dbase)) = *(const uint2*)o;
        }
        {
            float4 x = *(const float4*)(row + 1024 + lh * 64 + dbase);
            float ss = x.x * x.x + x.y * x.y + x.z * x.z + x.w * x.w;
            #pragma unroll
            for (int m = 1; m < 16; m <<= 1) ss += __shfl_xor(ss, m);
            float rn = 1.0f / sqrtf(ss * (1.0f / 64.0f) + eps);
            float xn0 = x.x * rn, xn1 = x.y * rn, xn2 = x.z * rn, xn3 = x.w * rn;
            float p0 = __shfl_xor(xn0, 8), p1 = __shfl_xor(xn1, 8);
            float p2 = __shfl_xor(xn2, 8), p3 = __shfl_xor(xn3, 8);
            u16 o[4] = {f2bf(xn0 * cosv[0] + sgn * p0 * sinv[0]),
                        f2bf(xn1 * cosv[1] + sgn * p1 * sinv[1]),
                        f2bf(xn2 * cosv[2] + sgn * p2 * sinv[2]),
                        f2bf(xn3 * cosv[3] + sgn * p3 * sinv[3])};
            *(uint2*)(Kb + (((size_t)(b * 4 + lh) * 2048 + s) * 64 + dbase)) = *(const uint2*)o;
        }
        {
            float4 x = *(const float4*)(row + 1280 + lh * 64 + dbase);
            u16 o[4] = {f2bf(x.x), f2bf(x.y), f2bf(x.z), f2bf(x.w)};
            int sl = wid * 2 + i;
            *(uint2*)(&Vs[sl][lh * 64 + dbase]) = *(const uint2*)o;
        }
    }
    __syncthreads();
    {
        int kvh = tid >> 6, d = tid & 63;
        int b0 = T0 >> 11, s0 = T0 & 2047;
        u16 tmp[8];
        #pragma unroll
        for (int sl = 0; sl < 8; ++sl) tmp[sl] = Vs[sl][kvh * 64 + d];
        u16* dst = Vt + ((size_t)(b0 * 4 + kvh) * 64 + d) * 2048 + s0;
        *(int4*)(dst) = *(const int4*)(tmp);
    }
}

// ============================================================================
// 4. Flash attention, split-K flash-decoding. Q-tile 128 (2 bands/wave),
//    K-tile 64, chunks of 1024 cols. bq<8: single chunk, write y directly.
//    bq>=8: two chunks writing fp32 partials (O, m, l); merged by `merge`.
//    Grid (32, 24): every block <= 16 iterations (uniform load, 3 blocks/CU).
// ============================================================================
__global__ __launch_bounds__(256) void attn(
    const u16* __restrict__ Qb, const u16* __restrict__ Kb,
    const u16* __restrict__ Vt, float* __restrict__ y,
    float* __restrict__ Opart, float2* __restrict__ ml) {
    __shared__ u16 Ks[2][64 * 64];
    __shared__ u16 Vsh[2][64 * 64];
    const int hb = blockIdx.x;
    const int h = hb & 15, b = hb >> 4, kvh = h >> 2;
    const int yid = blockIdx.y;
    int bq, c0;          // c0 = starting 64-tile of this chunk
    bool partial;
    if (yid < 16) { bq = 15 - (yid >> 1); c0 = (yid & 1) * 16; partial = true; }
    else          { bq = 23 - yid;        c0 = 0;              partial = false; }
    const int nj = partial ? (c0 ? (2 * bq + 2 - 16) : 16) : (2 * bq + 2);
    const int q0 = bq * 128;
    const int tid = threadIdx.x, lane = tid & 63, w = tid >> 6;
    const int quad = lane >> 4, l16 = lane & 15;

    const u16* Qg = Qb + ((size_t)(b * 16 + h) * 2048 + q0) * 64;
    const u16* Kg = Kb + (size_t)(b * 4 + kvh) * 2048 * 64;
    const u16* Vg = Vt + (size_t)(b * 4 + kvh) * 64 * 2048;

    // Q fragments straight from global (once): band bi2, half hf
    bf16x8 qa[2][2];
    #pragma unroll
    for (int bi2 = 0; bi2 < 2; ++bi2)
        #pragma unroll
        for (int hf = 0; hf < 2; ++hf)
            qa[bi2][hf] = *(const bf16x8*)(Qg + (size_t)(bi2 * 64 + w * 16 + l16) * 64 + hf * 32 + quad * 8);

    // staging geometry
    const int sr_ = w * 16 + (lane >> 3);
    const int sg_ = lane & 7;
    const int sld = w * 1024 + lane * 8;

    // stage first tile
    #pragma unroll
    for (int i = 0; i < 2; ++i) {
        int r = sr_ + i * 8;
        int g = sg_ ^ (r & 7);
        glds16(Kg + (size_t)(c0 * 64 + r) * 64 + g * 8, &Ks[0][0] + sld + i * 512);
        glds16(Vg + (size_t)r * 2048 + c0 * 64 + g * 8, &Vsh[0][0] + sld + i * 512);
    }
    __syncthreads();

    f32x4 o0[4], o1[4];
    f32x4 zero = {0.f, 0.f, 0.f, 0.f};
    #pragma unroll
    for (int t = 0; t < 4; ++t) { o0[t] = zero; o1[t] = zero; }
    float m0 = -INFINITY, l0 = 0.f, m1 = -INFINITY, l1 = 0.f;
    const float sc = 0.18033688011112042f;  // 0.125 * log2(e)

    for (int j = 0; j < nj; ++j) {
        if (j + 1 < nj) {
            int jj = (c0 + j + 1) * 64, bi = (j + 1) & 1;
            #pragma unroll
            for (int i = 0; i < 2; ++i) {
                int r = sr_ + i * 8;
                int g = sg_ ^ (r & 7);
                glds16(Kg + (size_t)(jj + r) * 64 + g * 8, &Ks[bi][0] + sld + i * 512);
                glds16(Vg + (size_t)r * 2048 + jj + g * 8, &Vsh[bi][0] + sld + i * 512);
            }
        }
        const u16* Kt = &Ks[j & 1][0];
        const u16* Vtl = &Vsh[j & 1][0];
        const int d0 = 8 * bq + w - 4 * (c0 + j);   // band0 diag t; band1 = d0+4
        const int d1 = d0 + 4;

        f32x4 st0[4], st1[4];
        #pragma unroll
        for (int t = 0; t < 4; ++t) {
            if (t <= d1) {
                int rk = t * 16 + l16;
                bf16x8 kb0 = *(const bf16x8*)(Kt + rk * 64 + (quad ^ (rk & 7)) * 8);
                bf16x8 kb1 = *(const bf16x8*)(Kt + rk * 64 + ((quad + 4) ^ (rk & 7)) * 8);
                f32x4 s1 = __builtin_amdgcn_mfma_f32_16x16x32_bf16(kb0, qa[1][0], zero, 0, 0, 0);
                s1 = __builtin_amdgcn_mfma_f32_16x16x32_bf16(kb1, qa[1][1], s1, 0, 0, 0);
                st1[t] = s1;
                if (t <= d0) {
                    f32x4 s0 = __builtin_amdgcn_mfma_f32_16x16x32_bf16(kb0, qa[0][0], zero, 0, 0, 0);
                    s0 = __builtin_amdgcn_mfma_f32_16x16x32_bf16(kb1, qa[0][1], s0, 0, 0, 0);
                    st0[t] = s0;
                }
            }
        }

        s16x4 pf0[4], pf1[4];
        // ---- band1 (always active) ----
        {
            float mx = -1e30f;
            #pragma unroll
            for (int t = 0; t < 4; ++t) {
                if (t <= d1) {
                    #pragma unroll
                    for (int r = 0; r < 4; ++r) {
                        float v = st1[t][r] * sc;
                        if (t == d1 && (quad * 4 + r > l16)) v = -1e30f;
                        st1[t][r] = v;
                        mx = fmaxf(mx, v);
                    }
                }
            }
            mx = fmaxf(mx, __shfl_xor(mx, 16));
            mx = fmaxf(mx, __shfl_xor(mx, 32));
            float mnew = fmaxf(m1, mx);
            float alpha1 = __builtin_amdgcn_exp2f(m1 - mnew);
            m1 = mnew;
            float rs = 0.f;
            #pragma unroll
            for (int t = 0; t < 4; ++t) {
                if (t <= d1) {
                    float p0 = __builtin_amdgcn_exp2f(st1[t][0] - mnew);
                    float p1 = __builtin_amdgcn_exp2f(st1[t][1] - mnew);
                    float p2 = __builtin_amdgcn_exp2f(st1[t][2] - mnew);
                    float p3 = __builtin_amdgcn_exp2f(st1[t][3] - mnew);
                    rs += (p0 + p1) + (p2 + p3);
                    pf1[t] = pack_bf4(p0, p1, p2, p3);
                }
            }
            rs += __shfl_xor(rs, 16);
            rs += __shfl_xor(rs, 32);
            l1 = l1 * alpha1 + rs;
            #pragma unroll
            for (int t = 0; t < 4; ++t) o1[t] *= alpha1;
        }
        // ---- band0 (skip when fully masked) ----
        if (d0 >= 0) {
            float mx = -1e30f;
            #pragma unroll
            for (int t = 0; t < 4; ++t) {
                if (t <= d0) {
                    #pragma unroll
                    for (int r = 0; r < 4; ++r) {
                        float v = st0[t][r] * sc;
                        if (t == d0 && (quad * 4 + r > l16)) v = -1e30f;
                        st0[t][r] = v;
                        mx = fmaxf(mx, v);
                    }
                }
            }
            mx = fmaxf(mx, __shfl_xor(mx, 16));
            mx = fmaxf(mx, __shfl_xor(mx, 32));
            float mnew = fmaxf(m0, mx);
            float alpha0 = __builtin_amdgcn_exp2f(m0 - mnew);
            m0 = mnew;
            float rs = 0.f;
            #pragma unroll
            for (int t = 0; t < 4; ++t) {
                if (t <= d0) {
                    float p0 = __builtin_amdgcn_exp2f(st0[t][0] - mnew);
                    float p1 = __builtin_amdgcn_exp2f(st0[t][1] - mnew);
                    float p2 = __builtin_amdgcn_exp2f(st0[t][2] - mnew);
                    float p3 = __builtin_amdgcn_exp2f(st0[t][3] - mnew);
                    rs += (p0 + p1) + (p2 + p3);
                    pf0[t] = pack_bf4(p0, p1, p2, p3);
                }
            }
            rs += __shfl_xor(rs, 16);
            rs += __shfl_xor(rs, 32);
            l0 = l0 * alpha0 + rs;
            #pragma unroll
            for (int t = 0; t < 4; ++t) o0[t] *= alpha0;
        }

        // PV: V frags shared by both bands
        #pragma unroll
        for (int dt = 0; dt < 4; ++dt) {
            int rv = dt * 16 + l16;
            #pragma unroll
            for (int kt = 0; kt < 4; ++kt) {
                if (kt <= d1) {
                    int gv = 2 * kt + (quad >> 1);
                    s16x4 va = *(const s16x4*)(Vtl + rv * 64 + (gv ^ (rv & 7)) * 8 + (quad & 1) * 4);
                    if (kt <= d0) o0[dt] = MFMA16(va, pf0[kt], o0[dt]);
                    o1[dt] = MFMA16(va, pf1[kt], o1[dt]);
                }
            }
        }
        __syncthreads();
    }

    if (!partial) {
        const float inv0 = 1.0f / l0, inv1 = 1.0f / l1;
        const size_t r0 = (size_t)b * 2048 + q0 + w * 16 + l16;
        #pragma unroll
        for (int dt = 0; dt < 4; ++dt) {
            f32x4 a = o0[dt] * inv0;
            f32x4 c = o1[dt] * inv1;
            *(f32x4*)(&y[r0 * 1024 + h * 64 + dt * 16 + quad * 4]) = a;
            *(f32x4*)(&y[(r0 + 64) * 1024 + h * 64 + dt * 16 + quad * 4]) = c;
        }
    } else {
        const int slot = (hb * 8 + (bq - 8)) * 2 + (c0 ? 1 : 0);
        float* Op = Opart + (size_t)slot * 8192;
        const int q = w * 16 + l16;
        #pragma unroll
        for (int dt = 0; dt < 4; ++dt) {
            *(f32x4*)(Op + q * 64 + dt * 16 + quad * 4) = o0[dt];
            *(f32x4*)(Op + (q + 64) * 64 + dt * 16 + quad * 4) = o1[dt];
        }
        if (quad == 0) {
            ml[slot * 128 + q]      = make_float2(m0, l0);
            ml[slot * 128 + q + 64] = make_float2(m1, l1);
        }
    }
}

// ============================================================================
// 5. merge: combine the two chunk-partials for bq>=8 into y.
// ============================================================================
__global__ __launch_bounds__(256) void merge(
    const float* __restrict__ Opart, const float2* __restrict__ ml,
    float* __restrict__ y) {
    const int hb = blockIdx.x, h = hb & 15, b = hb >> 4;
    const int bq = 8 + blockIdx.y;
    const int s0i = (hb * 8 + blockIdx.y) * 2;
    const int tid = threadIdx.x;
    const int q = tid >> 1, dh = (tid & 1) * 32;
    float2 a0 = ml[s0i * 128 + q];
    float2 a1 = ml[(s0i + 1) * 128 + q];
    float M = fmaxf(a0.x, a1.x);
    float w0 = __builtin_amdgcn_exp2f(a0.x - M);
    float w1 = __builtin_amdgcn_exp2f(a1.x - M);
    float inv = 1.0f / (w0 * a0.y + w1 * a1.y);
    w0 *= inv; w1 *= inv;
    const float* P0 = Opart + (size_t)s0i * 8192 + q * 64 + dh;
    const float* P1 = P0 + 8192;
    float* yo = y + ((size_t)b * 2048 + bq * 128 + q) * 1024 + h * 64 + dh;
    #pragma unroll
    for (int d = 0; d < 32; d += 4) {
        f32x4 x0 = *(const f32x4*)(P0 + d);
        f32x4 x1 = *(const f32x4*)(P1 + d);
        f32x4 r = x0 * w0 + x1 * w1;
        *(f32x4*)(yo + d) = r;
    }
}

// ============================================================================
// 6. Row RMSNorm (dim 1024) -> bf16
// ============================================================================
__global__ __launch_bounds__(256) void rmsnorm_rows(
    const float* __restrict__ y, u16* __restrict__ yb) {
    __shared__ float red[4];
    const int row = blockIdx.x, tid = threadIdx.x;
    const float* p = y + (size_t)row * 1024 + tid * 4;
    float4 v = *(const float4*)p;
    float ss = v.x * v.x + v.y * v.y + v.z * v.z + v.w * v.w;
    #pragma unroll
    for (int m = 1; m < 64; m <<= 1) ss += __shfl_xor(ss, m);
    if ((tid & 63) == 0) red[tid >> 6] = ss;
    __syncthreads();
    float tot = red[0] + red[1] + red[2] + red[3];
    float rn = 1.0f / sqrtf(tot * (1.0f / 1024.0f) + 1.1920929e-7f);
    u16 o[4] = {f2bf(v.x * rn), f2bf(v.y * rn), f2bf(v.z * rn), f2bf(v.w * rn)};
    *(uint2*)(yb + (size_t)row * 1024 + tid * 4) = *(const uint2*)o;
}

// ============================================================================
// launch — workspace re-colored by lifetime (peak 48.8 MB):
//   [0,        2.10M)  wproj_b           (prep -> gemm2)
//   [2.10M,   10.49M)  xb (prep->gemm1)  then Qb (fuse->attn)
//   [10.49M,  12.58M)  Kb                (fuse -> attn)
//   [12.58M,  14.68M)  Vt                (fuse -> attn)
//   [14.68M,  39.85M)  qkv (gemm1->fuse) then y@14.68M (attn/merge->rmsnorm)
//   [31.46M,  48.23M)  Opart (attn->merge) then yb@31.46M (rmsnorm->gemm2)
//   [39.85M,  42.99M)  wqkv_b            (prep -> gemm1)
//   [48.23M,  48.76M)  ml                (attn -> merge)
// ============================================================================
extern "C" void kernel_launch(void* const* d_in, const int* in_sizes, int n_in,
                              void* d_out, int out_size, void* d_ws, size_t ws_size,
                              hipStream_t stream) {
    const float* x      = (const float*)d_in[0];
    const float* w_qkv  = (const float*)d_in[1];
    const float* w_proj = (const float*)d_in[2];
    const float* q_gain = (const float*)d_in[3];
    float* out = (float*)d_out;
    char* ws = (char*)d_ws;

    u16*    wproj_b = (u16*)(ws);
    u16*    xb      = (u16*)(ws + 2097152);
    u16*    Qb      = (u16*)(ws + 2097152);
    u16*    Kb      = (u16*)(ws + 10485760);
    u16*    Vt      = (u16*)(ws + 12582912);
    float*  qkv     = (float*)(ws + 14680064);
    float*  y       = (float*)(ws + 14680064);
    float*  Opart   = (float*)(ws + 31457280);
    u16*    yb      = (u16*)(ws + 31457280);
    u16*    wqkv_b  = (u16*)(ws + 39845888);
    float2* mlb     = (float2*)(ws + 48234496);

    prep<<<12288, 256, 0, stream>>>(w_qkv, w_proj, x, wqkv_b, wproj_b, xb);
    gemm_bt<<<dim3(12, 32), 256, 0, stream>>>(xb, wqkv_b, qkv, 4096, 1536, 1024);
    fuse_qkv<<<512, 256, 0, stream>>>(qkv, q_gain, Qb, Kb, Vt);
    attn<<<dim3(32, 24), 256, 0, stream>>>(Qb, Kb, Vt, y, Opart, mlb);
    merge<<<dim3(32, 8), 256, 0, stream>>>(Opart, mlb, y);
    rmsnorm_rows<<<4096, 256, 0, stream>>>(y, yb);
    gemm_bt<<<dim3(8, 32), 256, 0, stream>>>(yb, wproj_b, out, 4096, 1024, 1024);
}

// Round 6
// 204.981 us; speedup vs baseline: 1.3288x; 1.1565x over previous
//
#include <hip/hip_runtime.h>
#include <cstdint>

typedef unsigned short u16;
typedef __bf16 bf16x8 __attribute__((ext_vector_type(8)));
typedef short s16x4 __attribute__((ext_vector_type(4)));
typedef int s32x2 __attribute__((ext_vector_type(2)));
typedef float f32x4 __attribute__((ext_vector_type(4)));

// ---- bf16 helpers (RTNE, matching XLA/ml_dtypes) ----
__device__ __forceinline__ u16 f2bf(float f) {
    unsigned u = __float_as_uint(f);
    u = (u + 0x7fffu + ((u >> 16) & 1u)) >> 16;
    return (u16)u;
}
__device__ __forceinline__ float bf2f(u16 h) {
    return __uint_as_float(((unsigned)h) << 16);
}

// async global->LDS, 16B per lane; LDS dest = wave-uniform base + lane*16
__device__ __forceinline__ void glds16(const u16* g, u16* l) {
    __builtin_amdgcn_global_load_lds(
        (const __attribute__((address_space(1))) void*)g,
        (__attribute__((address_space(3))) void*)l, 16, 0, 0);
}

// pack 4 positive floats -> 4 bf16 (round-half-up; ties-only diff vs RTNE)
__device__ __forceinline__ s16x4 pack_bf4(float p0, float p1, float p2, float p3) {
    unsigned a0 = __float_as_uint(p0) + 0x8000u;
    unsigned a1 = __float_as_uint(p1) + 0x8000u;
    unsigned a2 = __float_as_uint(p2) + 0x8000u;
    unsigned a3 = __float_as_uint(p3) + 0x8000u;
    s32x2 pk = {(int)__builtin_amdgcn_perm(a1, a0, 0x07060302u),
                (int)__builtin_amdgcn_perm(a3, a2, 0x07060302u)};
    return __builtin_bit_cast(s16x4, pk);
}

#if __has_builtin(__builtin_amdgcn_mfma_f32_16x16x16bf16_1k)
#define MFMA16(a, b, c) __builtin_amdgcn_mfma_f32_16x16x16bf16_1k(a, b, c, 0, 0, 0)
#else
static __device__ __forceinline__ f32x4 mfma16_asm(s16x4 a, s16x4 b, f32x4 c) {
    asm("v_mfma_f32_16x16x16_bf16 %0, %1, %2, %0" : "+v"(c) : "v"(a), "v"(b));
    return c;
}
#define MFMA16(a, b, c) mfma16_asm(a, b, c)
#endif

// ============================================================================
// 1. prep: ternary-quantize both weights (8 elems/lane) + cast x to bf16.
//    GRID = 1280 quant blocks + 2048 cast blocks = 3328.  (R5 bug: launched
//    5376 -> cast branch read 16MB past x -> page fault.)
// ============================================================================
__global__ __launch_bounds__(256) void prep(
    const float* __restrict__ w_qkv, const float* __restrict__ w_proj,
    const float* __restrict__ x,
    u16* __restrict__ wqkv_b, u16* __restrict__ wproj_b, u16* __restrict__ xb) {
    int bid = blockIdx.x;
    if (bid < 1280) {
        const float* w; u16* o; size_t base;
        if (bid < 768) { w = w_qkv; o = wqkv_b; base = (size_t)bid * 2048; }
        else { w = w_proj; o = wproj_b; base = (size_t)(bid - 768) * 2048; }
        size_t i = base + (size_t)threadIdx.x * 8;
        float4 A = *(const float4*)(w + i);
        float4 B = *(const float4*)(w + i + 4);
        float wf[8] = {A.x, A.y, A.z, A.w, B.x, B.y, B.z, B.w};
        float wbf[8], ab[8];
        #pragma unroll
        for (int e = 0; e < 8; ++e) { wbf[e] = bf2f(f2bf(wf[e])); ab[e] = fabsf(wbf[e]); }
        float s = ((ab[0] + ab[1]) + (ab[2] + ab[3])) + ((ab[4] + ab[5]) + (ab[6] + ab[7]));
        s += __shfl_xor(s, 1);
        s += __shfl_xor(s, 2);
        s += __shfl_xor(s, 4);   // 8-lane cluster = one 64-elem group
        float scale = bf2f(f2bf(s * (1.0f / 64.0f)));
        if (scale < 1e-8f) scale = 1e-8f;
        u16 ov[8];
        #pragma unroll
        for (int e = 0; e < 8; ++e) {
            float t = bf2f(f2bf(wbf[e] / scale));
            float q = rintf(t);
            q = fminf(1.0f, fmaxf(-1.0f, q));
            float d = bf2f(f2bf(q * scale - wbf[e]));
            ov[e] = f2bf(wbf[e] + d);
        }
        *(int4*)(o + i) = *(const int4*)ov;
    } else {
        size_t i = ((size_t)(bid - 1280) * 256 + threadIdx.x) * 8;
        float4 a = *(const float4*)(x + i);
        float4 b = *(const float4*)(x + i + 4);
        u16 o[8] = {f2bf(a.x), f2bf(a.y), f2bf(a.z), f2bf(a.w),
                    f2bf(b.x), f2bf(b.y), f2bf(b.z), f2bf(b.w)};
        *(int4*)(xb + i) = *(const int4*)o;
    }
}

// ============================================================================
// 2. GEMM: C[M,N] fp32 = A[M,K]bf16 @ B[N,K]bf16^T.  128x128 tile, BK=32,
//    glds staging with XOR((r>>1)&3) swizzle.
// ============================================================================
__global__ __launch_bounds__(256) void gemm_bt(
    const u16* __restrict__ A, const u16* __restrict__ B,
    float* __restrict__ C, int M, int N, int K) {
    __shared__ u16 As[128 * 32];
    __shared__ u16 Bs[128 * 32];
    const int tid = threadIdx.x;
    const int lane = tid & 63, w = tid >> 6;
    const int quad = lane >> 4, l16 = lane & 15;
    const int m0 = blockIdx.y * 128, n0 = blockIdx.x * 128;
    const int wm = (w >> 1) * 64, wn = (w & 1) * 64;
    const int sr_ = w * 32 + (lane >> 2);
    const int sg_ = lane & 3;
    u16* Ald = As + w * 1024 + lane * 8;
    u16* Bld = Bs + w * 1024 + lane * 8;

    f32x4 acc[4][4];
    f32x4 zero = {0.f, 0.f, 0.f, 0.f};
    #pragma unroll
    for (int i = 0; i < 4; ++i)
        #pragma unroll
        for (int j = 0; j < 4; ++j) acc[i][j] = zero;

    int aoff[4], boff[4];
    #pragma unroll
    for (int mi = 0; mi < 4; ++mi) {
        int r = wm + mi * 16 + l16;
        aoff[mi] = r * 32 + (quad ^ ((r >> 1) & 3)) * 8;
        int rb = wn + mi * 16 + l16;
        boff[mi] = rb * 32 + (quad ^ ((rb >> 1) & 3)) * 8;
    }

    for (int k0 = 0; k0 < K; k0 += 32) {
        __syncthreads();
        #pragma unroll
        for (int i = 0; i < 2; ++i) {
            int r = sr_ + i * 16;
            int g = sg_ ^ ((r >> 1) & 3);
            glds16(A + (size_t)(m0 + r) * K + k0 + g * 8, Ald + i * 512);
            glds16(B + (size_t)(n0 + r) * K + k0 + g * 8, Bld + i * 512);
        }
        __syncthreads();
        bf16x8 af[4], bfr[4];
        #pragma unroll
        for (int mi = 0; mi < 4; ++mi) af[mi]  = *(const bf16x8*)(As + aoff[mi]);
        #pragma unroll
        for (int ni = 0; ni < 4; ++ni) bfr[ni] = *(const bf16x8*)(Bs + boff[ni]);
        #pragma unroll
        for (int mi = 0; mi < 4; ++mi)
            #pragma unroll
            for (int ni = 0; ni < 4; ++ni)
                acc[mi][ni] = __builtin_amdgcn_mfma_f32_16x16x32_bf16(af[mi], bfr[ni], acc[mi][ni], 0, 0, 0);
    }
    #pragma unroll
    for (int mi = 0; mi < 4; ++mi)
        #pragma unroll
        for (int ni = 0; ni < 4; ++ni) {
            int rg = m0 + wm + mi * 16 + quad * 4;
            int cg = n0 + wn + ni * 16 + l16;
            float* cp = C + (size_t)rg * N + cg;
            #pragma unroll
            for (int r = 0; r < 4; ++r) cp[(size_t)r * N] = acc[mi][ni][r];
        }
}

// ============================================================================
// 3. Fusion: head-RMSNorm + RoPE + gain (pre-scaled by 0.125*log2e for Q);
//    8 tokens/block. Fast __cosf/__sinf.
// ============================================================================
__global__ __launch_bounds__(256) void fuse_qkv(
    const float* __restrict__ qkv, const float* __restrict__ gain,
    u16* __restrict__ Qb, u16* __restrict__ Kb, u16* __restrict__ Vt) {
    __shared__ u16 Vs[8][264];
    const int tid = threadIdx.x;
    const int lane = tid & 63, wid = tid >> 6;
    const int lh = lane >> 4, l16 = lane & 15;
    const int T0 = blockIdx.x * 8;
    const int dbase = l16 * 4;
    const bool hi = dbase >= 32;
    const int ibase = hi ? dbase - 32 : dbase;
    const float sgn = hi ? -1.0f : 1.0f;
    const float eps = 1.1920929e-7f;
    const float sc = 0.18033688011112042f;  // 0.125 * log2(e)

    float invf[4];
    #pragma unroll
    for (int j = 0; j < 4; ++j)
        invf[j] = (float)(1.0 / pow(10000.0, (double)(ibase + j) / 32.0));

    #pragma unroll
    for (int i = 0; i < 2; ++i) {
        int tok = T0 + wid * 2 + i;
        int b = tok >> 11, s = tok & 2047;
        float cosv[4], sinv[4];
        #pragma unroll
        for (int j = 0; j < 4; ++j) {
            float fr = (float)s * invf[j];
            cosv[j] = __cosf(fr);
            sinv[j] = __sinf(fr);
        }
        const float* row = qkv + (size_t)tok * 1536;
        #pragma unroll
        for (int p = 0; p < 4; ++p) {
            int h = p * 4 + lh;
            float4 x = *(const float4*)(row + h * 64 + dbase);
            float ss = x.x * x.x + x.y * x.y + x.z * x.z + x.w * x.w;
            #pragma unroll
            for (int m = 1; m < 16; m <<= 1) ss += __shfl_xor(ss, m);
            float rn = 1.0f / sqrtf(ss * (1.0f / 64.0f) + eps);
            float xn0 = x.x * rn, xn1 = x.y * rn, xn2 = x.z * rn, xn3 = x.w * rn;
            float p0 = __shfl_xor(xn0, 8), p1 = __shfl_xor(xn1, 8);
            float p2 = __shfl_xor(xn2, 8), p3 = __shfl_xor(xn3, 8);
            float g = gain[h] * sc;
            u16 o[4] = {f2bf((xn0 * cosv[0] + sgn * p0 * sinv[0]) * g),
                        f2bf((xn1 * cosv[1] + sgn * p1 * sinv[1]) * g),
                        f2bf((xn2 * cosv[2] + sgn * p2 * sinv[2]) * g),
                        f2bf((xn3 * cosv[3] + sgn * p3 * sinv[3]) * g)};
            *(uint2*)(Qb + (((size_t)(b * 16 + h) * 2048 + s) * 64 + dbase)) = *(const uint2*)o;
        }
        {
            float4 x = *(const float4*)(row + 1024 + lh * 64 + dbase);
            float ss = x.x * x.x + x.y * x.y + x.z * x.z + x.w * x.w;
            #pragma unroll
            for (int m = 1; m < 16; m <<= 1) ss += __shfl_xor(ss, m);
            float rn = 1.0f / sqrtf(ss * (1.0f / 64.0f) + eps);
            float xn0 = x.x * rn, xn1 = x.y * rn, xn2 = x.z * rn, xn3 = x.w * rn;
            float p0 = __shfl_xor(xn0, 8), p1 = __shfl_xor(xn1, 8);
            float p2 = __shfl_xor(xn2, 8), p3 = __shfl_xor(xn3, 8);
            u16 o[4] = {f2bf(xn0 * cosv[0] + sgn * p0 * sinv[0]),
                        f2bf(xn1 * cosv[1] + sgn * p1 * sinv[1]),
                        f2bf(xn2 * cosv[2] + sgn * p2 * sinv[2]),
                        f2bf(xn3 * cosv[3] + sgn * p3 * sinv[3])};
            *(uint2*)(Kb + (((size_t)(b * 4 + lh) * 2048 + s) * 64 + dbase)) = *(const uint2*)o;
        }
        {
            float4 x = *(const float4*)(row + 1280 + lh * 64 + dbase);
            u16 o[4] = {f2bf(x.x), f2bf(x.y), f2bf(x.z), f2bf(x.w)};
            int sl = wid * 2 + i;
            *(uint2*)(&Vs[sl][lh * 64 + dbase]) = *(const uint2*)o;
        }
    }
    __syncthreads();
    {
        int kvh = tid >> 6, d = tid & 63;
        int b0 = T0 >> 11, s0 = T0 & 2047;
        u16 tmp[8];
        #pragma unroll
        for (int sl = 0; sl < 8; ++sl) tmp[sl] = Vs[sl][kvh * 64 + d];
        u16* dst = Vt + ((size_t)(b0 * 4 + kvh) * 64 + d) * 2048 + s0;
        *(int4*)(dst) = *(const int4*)(tmp);
    }
}

// ============================================================================
// 4. Flash attention: 512 threads, 8 waves, ONE 16-row band per wave
//    (Q-tile 128). Split-K chunks of 1024 (grid 32x24). Diag-first K-loop
//    with ballot-gated alpha rescale; Q pre-scaled by 0.125*log2e.
// ============================================================================
__global__ __launch_bounds__(512, 4) void attn(
    const u16* __restrict__ Qb, const u16* __restrict__ Kb,
    const u16* __restrict__ Vt, float* __restrict__ y,
    float* __restrict__ Opart, float2* __restrict__ ml) {
    __shared__ u16 Ks[2][64 * 64];
    __shared__ u16 Vsh[2][64 * 64];
    const int hb = blockIdx.x;
    const int h = hb & 15, b = hb >> 4, kvh = h >> 2;
    const int yid = blockIdx.y;
    int bq, c0; bool partial;
    if (yid < 16) { bq = 15 - (yid >> 1); c0 = (yid & 1) * 16; partial = true; }
    else          { bq = 23 - yid;        c0 = 0;              partial = false; }
    const int nj = partial ? (c0 ? (2 * bq - 14) : 16) : (2 * bq + 2);
    const int q0 = bq * 128;
    const int tid = threadIdx.x, lane = tid & 63, w = tid >> 6;  // w: 0..7
    const int quad = lane >> 4, l16 = lane & 15;

    const u16* Qg = Qb + ((size_t)(b * 16 + h) * 2048 + q0) * 64;
    const u16* Kg = Kb + (size_t)(b * 4 + kvh) * 2048 * 64;
    const u16* Vg = Vt + (size_t)(b * 4 + kvh) * 64 * 2048;

    // this wave's Q fragments (rows w*16 + l16)
    const bf16x8 qa0 = *(const bf16x8*)(Qg + (size_t)(w * 16 + l16) * 64 + quad * 8);
    const bf16x8 qa1 = *(const bf16x8*)(Qg + (size_t)(w * 16 + l16) * 64 + 32 + quad * 8);

    // staging: 1 glds16/thread for K and V; source col-group XOR(row&7)
    const int sr = tid >> 3;
    const int sg = (tid & 7) ^ (sr & 7);
    u16* kd[2] = {&Ks[0][0] + tid * 8, &Ks[1][0] + tid * 8};
    u16* vd[2] = {&Vsh[0][0] + tid * 8, &Vsh[1][0] + tid * 8};

    {   // stage tile nj-1 (the diagonal-most of this chunk)
        int c = (c0 + nj - 1) * 64;
        glds16(Kg + (size_t)(c + sr) * 64 + sg * 8, kd[(nj - 1) & 1]);
        glds16(Vg + (size_t)sr * 2048 + c + sg * 8, vd[(nj - 1) & 1]);
    }
    __syncthreads();

    f32x4 o[4];
    f32x4 zero = {0.f, 0.f, 0.f, 0.f};
    #pragma unroll
    for (int t = 0; t < 4; ++t) o[t] = zero;
    float m = -INFINITY, l = 0.f;

    for (int jj = nj - 1; jj >= 0; --jj) {
        if (jj > 0) {
            int c = (c0 + jj - 1) * 64;
            glds16(Kg + (size_t)(c + sr) * 64 + sg * 8, kd[(jj - 1) & 1]);
            glds16(Vg + (size_t)sr * 2048 + c + sg * 8, vd[(jj - 1) & 1]);
        }
        const u16* Kt = (jj & 1) ? &Ks[1][0] : &Ks[0][0];
        const u16* Vl = (jj & 1) ? &Vsh[1][0] : &Vsh[0][0];
        const int d = 8 * bq + w - 4 * (c0 + jj);   // wave-uniform diag tile idx
        if (d >= 0) {
            const int tmax = d < 3 ? d : 3;
            f32x4 st[4];
            #pragma unroll
            for (int t = 0; t < 4; ++t) {
                if (t <= tmax) {
                    int rk = t * 16 + l16;
                    bf16x8 kb0 = *(const bf16x8*)(Kt + rk * 64 + ((quad ^ (rk & 7)) * 8));
                    bf16x8 kb1 = *(const bf16x8*)(Kt + rk * 64 + (((quad + 4) ^ (rk & 7)) * 8));
                    f32x4 s = __builtin_amdgcn_mfma_f32_16x16x32_bf16(kb0, qa0, zero, 0, 0, 0);
                    s = __builtin_amdgcn_mfma_f32_16x16x32_bf16(kb1, qa1, s, 0, 0, 0);
                    if (t == d) {   // diagonal tile: causal mask (uniform branch)
                        #pragma unroll
                        for (int r = 0; r < 4; ++r)
                            if (quad * 4 + r > l16) s[r] = -1e30f;
                    }
                    st[t] = s;
                }
            }
            float mx = -1e30f;
            #pragma unroll
            for (int t = 0; t < 4; ++t)
                if (t <= tmax)
                    mx = fmaxf(mx, fmaxf(fmaxf(st[t][0], st[t][1]), fmaxf(st[t][2], st[t][3])));
            mx = fmaxf(mx, __shfl_xor(mx, 16));
            mx = fmaxf(mx, __shfl_xor(mx, 32));
            if (__any(mx > m)) {     // rescale only when some row's max moved
                float mnew = fmaxf(m, mx);
                float alpha = __builtin_amdgcn_exp2f(m - mnew);
                l *= alpha;
                #pragma unroll
                for (int t = 0; t < 4; ++t) o[t] *= alpha;
                m = mnew;
            }
            float rs = 0.f;
            s16x4 pf[4];
            #pragma unroll
            for (int t = 0; t < 4; ++t) {
                if (t <= tmax) {
                    float p0 = __builtin_amdgcn_exp2f(st[t][0] - m);
                    float p1 = __builtin_amdgcn_exp2f(st[t][1] - m);
                    float p2 = __builtin_amdgcn_exp2f(st[t][2] - m);
                    float p3 = __builtin_amdgcn_exp2f(st[t][3] - m);
                    rs += (p0 + p1) + (p2 + p3);
                    pf[t] = pack_bf4(p0, p1, p2, p3);
                }
            }
            rs += __shfl_xor(rs, 16);
            rs += __shfl_xor(rs, 32);
            l += rs;
            #pragma unroll
            for (int dt = 0; dt < 4; ++dt) {
                int rv = dt * 16 + l16;
                #pragma unroll
                for (int kt = 0; kt < 4; ++kt) {
                    if (kt <= tmax) {
                        int gv = 2 * kt + (quad >> 1);
                        s16x4 va = *(const s16x4*)(Vl + rv * 64 + ((gv ^ (rv & 7)) * 8) + (quad & 1) * 4);
                        o[dt] = MFMA16(va, pf[kt], o[dt]);
                    }
                }
            }
        }
        __syncthreads();
    }

    const int q = w * 16 + l16;
    if (!partial) {
        const float inv = 1.0f / l;
        const size_t row = (size_t)b * 2048 + q0 + q;
        #pragma unroll
        for (int dt = 0; dt < 4; ++dt) {
            f32x4 a = o[dt] * inv;
            *(f32x4*)(&y[row * 1024 + h * 64 + dt * 16 + quad * 4]) = a;
        }
    } else {
        const int slot = (hb * 8 + (bq - 8)) * 2 + (c0 ? 1 : 0);
        float* Op = Opart + (size_t)slot * 8192;
        #pragma unroll
        for (int dt = 0; dt < 4; ++dt)
            *(f32x4*)(Op + q * 64 + dt * 16 + quad * 4) = o[dt];
        if (quad == 0) ml[slot * 128 + q] = make_float2(m, l);
    }
}

// ============================================================================
// 5. rmsnorm_merge: rows s<1024 read y; rows s>=1024 combine the two split-K
//    partials inline. Output bf16 row-normalized.
// ============================================================================
__global__ __launch_bounds__(256) void rmsnorm_merge(
    const float* __restrict__ y, const float* __restrict__ Opart,
    const float2* __restrict__ ml, u16* __restrict__ yb) {
    __shared__ float red[4];
    const int row = blockIdx.x, tid = threadIdx.x;
    const int b = row >> 11, s = row & 2047;
    float4 v;
    if (s < 1024) {
        v = *(const float4*)(y + (size_t)row * 1024 + tid * 4);
    } else {
        const int bq = s >> 7, q = s & 127;
        const int e = tid * 4, h = e >> 6, dh = e & 63;
        const int slot = ((b * 16 + h) * 8 + (bq - 8)) * 2;
        float2 a0 = ml[slot * 128 + q];
        float2 a1 = ml[(slot + 1) * 128 + q];
        float M = fmaxf(a0.x, a1.x);
        float w0 = __builtin_amdgcn_exp2f(a0.x - M);
        float w1 = __builtin_amdgcn_exp2f(a1.x - M);
        float inv = 1.0f / (w0 * a0.y + w1 * a1.y);
        w0 *= inv; w1 *= inv;
        const float* P0 = Opart + (size_t)slot * 8192 + q * 64 + dh;
        f32x4 x0 = *(const f32x4*)P0;
        f32x4 x1 = *(const f32x4*)(P0 + 8192);
        f32x4 r = x0 * w0 + x1 * w1;
        v.x = r[0]; v.y = r[1]; v.z = r[2]; v.w = r[3];
    }
    float ss = v.x * v.x + v.y * v.y + v.z * v.z + v.w * v.w;
    #pragma unroll
    for (int m = 1; m < 64; m <<= 1) ss += __shfl_xor(ss, m);
    if ((tid & 63) == 0) red[tid >> 6] = ss;
    __syncthreads();
    float tot = red[0] + red[1] + red[2] + red[3];
    float rn = 1.0f / sqrtf(tot * (1.0f / 1024.0f) + 1.1920929e-7f);
    u16 o[4] = {f2bf(v.x * rn), f2bf(v.y * rn), f2bf(v.z * rn), f2bf(v.w * rn)};
    *(uint2*)(yb + (size_t)row * 1024 + tid * 4) = *(const uint2*)o;
}

// ============================================================================
// launch — workspace (peak 48.8 MB):
//   [0,      2.10M)  wproj_b  (prep -> gemm2)
//   [2.10M, 10.49M)  xb (prep->gemm1) -> Qb (fuse->attn) -> yb (rms->gemm2)
//   [10.49M,13.64M)  wqkv_b (prep->gemm1); then Kb@10.49M (fuse->attn)
//   [12.58M,14.68M)  Vt (fuse->attn)
//   [14.68M,39.85M)  qkv (gemm1->fuse); then y@14.68M..31.46M (attn->rms)
//   [31.46M,48.23M)  Opart (attn->rms)
//   [48.23M,48.76M)  ml (attn->rms)
// ============================================================================
extern "C" void kernel_launch(void* const* d_in, const int* in_sizes, int n_in,
                              void* d_out, int out_size, void* d_ws, size_t ws_size,
                              hipStream_t stream) {
    const float* x      = (const float*)d_in[0];
    const float* w_qkv  = (const float*)d_in[1];
    const float* w_proj = (const float*)d_in[2];
    const float* q_gain = (const float*)d_in[3];
    float* out = (float*)d_out;
    char* ws = (char*)d_ws;

    u16*    wproj_b = (u16*)(ws);
    u16*    xb      = (u16*)(ws + 2097152);
    u16*    Qb      = (u16*)(ws + 2097152);
    u16*    yb      = (u16*)(ws + 2097152);
    u16*    wqkv_b  = (u16*)(ws + 10485760);
    u16*    Kb      = (u16*)(ws + 10485760);
    u16*    Vt      = (u16*)(ws + 12582912);
    float*  qkv     = (float*)(ws + 14680064);
    float*  y       = (float*)(ws + 14680064);
    float*  Opart   = (float*)(ws + 31457280);
    float2* mlb     = (float2*)(ws + 48234496);

    prep<<<3328, 256, 0, stream>>>(w_qkv, w_proj, x, wqkv_b, wproj_b, xb);
    gemm_bt<<<dim3(12, 32), 256, 0, stream>>>(xb, wqkv_b, qkv, 4096, 1536, 1024);
    fuse_qkv<<<512, 256, 0, stream>>>(qkv, q_gain, Qb, Kb, Vt);
    attn<<<dim3(32, 24), 512, 0, stream>>>(Qb, Kb, Vt, y, Opart, mlb);
    rmsnorm_merge<<<4096, 256, 0, stream>>>(y, Opart, mlb, yb);
    gemm_bt<<<dim3(8, 32), 256, 0, stream>>>(yb, wproj_b, out, 4096, 1024, 1024);
}